// Round 5
// baseline (158.396 us; speedup 1.0000x reference)
//
#include <hip/hip_runtime.h>

// TripleGenerator: segmented triu-combinations.
// out = [idx_i (12M) | idx_j (12M) | idx_k (12M)] int32, 144 MB pure-write.
//
// R5 (two untested levers on the proven R4 structure):
//  1. nontemporal stores in the stream-specialized persistent writer --
//     bypass L2 write-allocate / dirty-poison-line eviction (NT was only
//     ever tried in the regressed R2 structure; confounded there).
//  2. guess-then-verify lower_bound for starts: 2 loads on the uniform
//     input (vs 21-deep dependent chain), exact binary-search fallback.

constexpr int K      = 16;                // neighbors/atom
constexpr int T_PER  = K * (K - 1) / 2;   // 120
constexpr int GROUPS = T_PER / 4;         // 30 int4 groups per atom

typedef int iv4 __attribute__((ext_vector_type(4)));

// Packed (u,v) template: entry r holds bytes {t=4r..4r+3} of pu in u[r], pv in v[r].
struct Tbl { unsigned u[GROUPS]; unsigned v[GROUPS]; };
constexpr Tbl make_tbl() {
    Tbl t{};
    int idx = 0;
    for (int a = 0; a < K; ++a)
        for (int b = a + 1; b < K; ++b) {
            t.u[idx / 4] |= (unsigned)a << ((idx % 4) * 8);
            t.v[idx / 4] |= (unsigned)b << ((idx % 4) * 8);
            ++idx;
        }
    return t;
}
__device__ constexpr Tbl TBL = make_tbl();

// Pass 1: starts[a] = lower_bound(pair_i, a), exact for any sorted pair_i
// (== cumsum(counts)-counts incl. empty segments). Fast path: probe the
// expected position a*m/n_atoms and its predecessor -- 2 loads when the
// neighbor count is uniform (the benchmark input); otherwise narrow the
// bracket and fall back to binary search.
__global__ void starts_kernel(const int* __restrict__ pair_i, int* __restrict__ starts,
                              int n_atoms, int m) {
    int a = blockIdx.x * blockDim.x + threadIdx.x;
    if (a >= n_atoms) return;

    int lo = 0, hi = m;
    int g = (int)(((long long)a * m) / n_atoms);
    if (g > m - 1) g = m - 1;
    if (pair_i[g] >= a) {
        if (g == 0 || pair_i[g - 1] < a) { starts[a] = g; return; }  // uniform fast path
        hi = g;
    } else {
        lo = g + 1;
    }
    while (lo < hi) {
        int mid = (lo + hi) >> 1;
        if (pair_i[mid] < a) lo = mid + 1; else hi = mid;
    }
    starts[a] = lo;
}

// Pass 2: persistent, stream-specialized, NONTEMPORAL stores.
__global__ __launch_bounds__(256)
void gen_split(const int* __restrict__ starts, int* __restrict__ out,
               int per_arr_groups) {
    const int s      = blockIdx.x % 3;            // stream id
    const int b      = blockIdx.x / 3;
    const int nb3    = gridDim.x / 3;             // blocks per stream
    const int stride = nb3 * blockDim.x;

    iv4* o = (iv4*)out + (size_t)s * per_arr_groups;

    if (s == 0) {
        for (int g = b * blockDim.x + threadIdx.x; g < per_arr_groups; g += stride) {
            const int atom = g / GROUPS;           // magic-mul const-div
            iv4 v; v[0] = atom; v[1] = atom; v[2] = atom; v[3] = atom;
            __builtin_nontemporal_store(v, &o[g]);
        }
    } else {
        const unsigned* __restrict__ tb = (s == 1) ? TBL.u : TBL.v;
        for (int g = b * blockDim.x + threadIdx.x; g < per_arr_groups; g += stride) {
            const int atom  = g / GROUPS;
            const int r     = g - atom * GROUPS;
            const int start = starts[atom];        // L2-hit, heavily shared
            const unsigned ub = tb[r];             // 120B L1-resident table
            iv4 v;
            v[0] = start + (int)(ub & 0xff);
            v[1] = start + (int)((ub >> 8)  & 0xff);
            v[2] = start + (int)((ub >> 16) & 0xff);
            v[3] = start + (int)((ub >> 24) & 0xff);
            __builtin_nontemporal_store(v, &o[g]);
        }
    }
}

extern "C" void kernel_launch(void* const* d_in, const int* in_sizes, int n_in,
                              void* d_out, int out_size, void* d_ws, size_t ws_size,
                              hipStream_t stream) {
    const int* pair_i  = (const int*)d_in[0];
    const int  m       = in_sizes[0];   // n_atoms * K
    const int  n_atoms = m / K;         // 100,000

    int* out = (int*)d_out;
    const int per_arr_groups = n_atoms * GROUPS;   // 3,000,000

    int* starts = (int*)d_ws;                      // 400 KB of scratch
    {
        const int b1 = 256;
        starts_kernel<<<(n_atoms + b1 - 1) / b1, b1, 0, stream>>>(pair_i, starts, n_atoms, m);
    }

    // 3072 blocks: 1024 per stream, 256 thr, ~11.4 int4-groups per thread.
    gen_split<<<3072, 256, 0, stream>>>(starts, out, per_arr_groups);
}